// Round 1
// baseline (138.645 us; speedup 1.0000x reference)
//
#include <hip/hip_runtime.h>
#include <hip/hip_bf16.h>
#include <stdint.h>

// NTXentLoss: B=4096, D=512, N=8192, tau=0.07, out = scalar mean loss.
// loss_i = -sim[i, i^B] + M + log( sum_{j != i} exp(sim_ij - M) ),  M = 1/tau
//
// R3: ksim rebuilt as a 256^2-tile, 8-wave, counted-vmcnt phase pipeline
// (T3+T4+T5 from the technique catalog). BK=32, 4-slot LDS ring (128 KiB),
// prefetch depth 2 K-tiles, s_waitcnt vmcnt(4) once per K-tile (never 0 in
// the main loop), raw s_barrier + lgkmcnt(0) + setprio(1) around each
// 16-MFMA cluster. 64 B LDS rows -> bank-even ds_read_b128 (no swizzle
// needed, global_load_lds dest stays linear). Epilogue reduces partials in
// LDS first: 2 global atomics per row per block. XCD-chunked block swizzle.

#define N_TOT   8192
#define B_HALF  4096
#define DDIM    512
#define INV_TAU 14.285714285714286f   // 1/0.07 == fixed logsumexp offset M
#define TTILES  32                    // 8192 / 256
#define NKT     16                    // 512 / 32

typedef __bf16 bf16x8 __attribute__((ext_vector_type(8)));
typedef __bf16 bf16x4 __attribute__((ext_vector_type(4)));
typedef float  floatx4 __attribute__((ext_vector_type(4)));

__device__ __forceinline__ void gl2lds16(const void* g, void* l) {
    __builtin_amdgcn_global_load_lds(
        (const __attribute__((address_space(1))) void*)g,
        (__attribute__((address_space(3))) void*)l, 16, 0, 0);
}

#define S_BARRIER() asm volatile("s_barrier" ::: "memory")
#define LGKM0()     do { asm volatile("s_waitcnt lgkmcnt(0)" ::: "memory"); \
                         __builtin_amdgcn_sched_barrier(0); } while (0)
#define VMCNT4()    asm volatile("s_waitcnt vmcnt(4)" ::: "memory")
#define VMCNT0()    asm volatile("s_waitcnt vmcnt(0)" ::: "memory")
#define VM_NONE()   do {} while (0)

// ---------------- kernel 1: normalize rows, fp32 -> bf16 z; zero row_sums ----
__global__ __launch_bounds__(256) void knorm(const float* __restrict__ anchor,
                                             const float* __restrict__ positive,
                                             __bf16* __restrict__ z,
                                             float* __restrict__ row_sums) {
    const int row  = blockIdx.x * 4 + (threadIdx.x >> 6);
    const int lane = threadIdx.x & 63;
    if (lane == 0) row_sums[row] = 0.0f;   // replaces hipMemsetAsync
    const float* src = (row < B_HALF) ? (anchor + (size_t)row * DDIM)
                                      : (positive + (size_t)(row - B_HALF) * DDIM);
    float4 v0 = ((const float4*)src)[lane];
    float4 v1 = ((const float4*)src)[lane + 64];
    float ss = v0.x*v0.x + v0.y*v0.y + v0.z*v0.z + v0.w*v0.w
             + v1.x*v1.x + v1.y*v1.y + v1.z*v1.z + v1.w*v1.w;
    #pragma unroll
    for (int m = 1; m < 64; m <<= 1) ss += __shfl_xor(ss, m, 64);
    const float inv = 1.0f / fmaxf(sqrtf(ss), 1e-8f);
    bf16x4 o0, o1;
    o0[0] = (__bf16)(v0.x*inv); o0[1] = (__bf16)(v0.y*inv);
    o0[2] = (__bf16)(v0.z*inv); o0[3] = (__bf16)(v0.w*inv);
    o1[0] = (__bf16)(v1.x*inv); o1[1] = (__bf16)(v1.y*inv);
    o1[2] = (__bf16)(v1.z*inv); o1[3] = (__bf16)(v1.w*inv);
    bf16x4* dst = (bf16x4*)(z + (size_t)row * DDIM);
    dst[lane]      = o0;
    dst[lane + 64] = o1;
}

// ---------------- kernel 2: upper-triangle 256x256 sim tiles, fused exp-sum --
// Grid 528 = 32*33/2 tile-pairs (rt <= ct). 512 threads = 8 waves (2M x 4N).
// Per wave: 128x64 of C as acc[8][4] 16x16x32 fragments. LDS: 4 K-slots of
// (A 256x32 + B 256x32) bf16 = 4 x 32 KiB.
__global__ __launch_bounds__(512, 2) void ksim(const __bf16* __restrict__ z,
                                               float* __restrict__ row_sums,
                                               float* __restrict__ pos_sims) {
    // XCD-chunked bijective swizzle (528 = 8 * 66), then triangular decode.
    int bid = (int)blockIdx.x;
    bid = (bid & 7) * 66 + (bid >> 3);
    int rem = bid, rt = 0;
    while (rem >= TTILES - rt) { rem -= TTILES - rt; rt++; }
    const int ct = rt + rem;
    const bool diag = (rt == ct);
    const bool posb = (ct == rt + 16);   // pos pair (i, i+4096) lives here

    const int r0 = rt * 256, c0 = ct * 256;
    const int tid  = threadIdx.x;
    const int w    = tid >> 6, lane = tid & 63;
    const int quad = lane >> 4, nlo = lane & 15;
    const int wr   = w >> 2,   wc  = w & 3;

    __shared__ __align__(16) char smem[4][32768];   // slot = [A 16K][B 16K]

    // staging: per wave-instruction 16 rows x 64 B contiguous; LDS dest is
    // wave-uniform base + lane*16 (global_load_lds constraint).
    // thread covers global (row = base + w*16 + lane/4, k-chunk = lane&3).
    const __bf16* zA = z + (size_t)(r0 + w * 16 + (lane >> 2)) * DDIM + (lane & 3) * 8;
    const __bf16* zB = z + (size_t)(c0 + w * 16 + (lane >> 2)) * DDIM + (lane & 3) * 8;

#define STAGE_A(T2) do { char* s_ = smem[(T2) & 3]; const int kb_ = (T2) * 32;   \
        gl2lds16(zA + kb_,              s_ + w * 1024);                          \
        gl2lds16(zA + 128 * DDIM + kb_, s_ + 8192 + w * 1024); } while (0)
#define STAGE_B(T2) do { char* s_ = smem[(T2) & 3]; const int kb_ = (T2) * 32;   \
        gl2lds16(zB + kb_,              s_ + 16384 + w * 1024);                  \
        gl2lds16(zB + 128 * DDIM + kb_, s_ + 16384 + 8192 + w * 1024); } while (0)

    floatx4 acc[8][4];
    #pragma unroll
    for (int a = 0; a < 8; a++)
        #pragma unroll
        for (int b = 0; b < 4; b++) acc[a][b] = (floatx4){0.f, 0.f, 0.f, 0.f};

    // prologue: tiles 0 and 1 in flight (8 loads/thread), ensure tile 0 ready.
    STAGE_A(0); STAGE_B(0);
    STAGE_A(1); STAGE_B(1);
    VMCNT4();          // oldest 4 (tile 0) complete; tile 1's 4 stay in flight
    S_BARRIER();

    // Per K-tile: 2 phases x {ds_read frags | issue prefetch | barrier |
    // lgkm(0) | setprio(1) 16 MFMA setprio(0) | barrier}; vmcnt(4) once at
    // phase-1 end guarantees tile t+1 resident before its first read.
#define KTILE(T, DO_STAGE, VMW) do {                                                  \
        char* As_ = smem[(T) & 3];                                                    \
        char* Bs_ = As_ + 16384;                                                      \
        bf16x8 af[4], bfr[4];                                                         \
        /* phase 0: rows wr*128 + 0..63 */                                            \
        _Pragma("unroll") for (int mi = 0; mi < 4; mi++)                              \
            af[mi] = *(const bf16x8*)(As_ + (wr * 128 + mi * 16 + nlo) * 64 + quad * 16); \
        _Pragma("unroll") for (int ni = 0; ni < 4; ni++)                              \
            bfr[ni] = *(const bf16x8*)(Bs_ + (wc * 64 + ni * 16 + nlo) * 64 + quad * 16); \
        if (DO_STAGE) STAGE_A((T) + 2);                                               \
        S_BARRIER(); LGKM0();                                                         \
        __builtin_amdgcn_s_setprio(1);                                                \
        _Pragma("unroll") for (int mi = 0; mi < 4; mi++)                              \
            _Pragma("unroll") for (int ni = 0; ni < 4; ni++)                          \
                acc[mi][ni] = __builtin_amdgcn_mfma_f32_16x16x32_bf16(                \
                    af[mi], bfr[ni], acc[mi][ni], 0, 0, 0);                           \
        __builtin_amdgcn_s_setprio(0);                                                \
        S_BARRIER();                                                                  \
        /* phase 1: rows wr*128 + 64..127 (bfr reused from regs) */                   \
        _Pragma("unroll") for (int mi = 0; mi < 4; mi++)                              \
            af[mi] = *(const bf16x8*)(As_ + (wr * 128 + 64 + mi * 16 + nlo) * 64 + quad * 16); \
        if (DO_STAGE) STAGE_B((T) + 2);                                               \
        S_BARRIER(); LGKM0();                                                         \
        __builtin_amdgcn_s_setprio(1);                                                \
        _Pragma("unroll") for (int mi = 0; mi < 4; mi++)                              \
            _Pragma("unroll") for (int ni = 0; ni < 4; ni++)                          \
                acc[4 + mi][ni] = __builtin_amdgcn_mfma_f32_16x16x32_bf16(            \
                    af[mi], bfr[ni], acc[4 + mi][ni], 0, 0, 0);                       \
        __builtin_amdgcn_s_setprio(0);                                                \
        VMW();                                                                        \
        S_BARRIER();                                                                  \
    } while (0)

    for (int t = 0; t < NKT - 2; ++t) KTILE(t, true, VMCNT4);
    KTILE(NKT - 2, false, VMCNT0);
    KTILE(NKT - 1, false, VM_NONE);

    // ---------------- epilogue: exp, exclusions, LDS partial-reduce ----------
    __syncthreads();                       // all slot reads done; smem reusable
    float* rbuf = (float*)smem;            // [256][4] : row partial per wc-wave
    float* cbuf = (float*)(smem[0] + 4096);// [256][2] : col partial per wr-wave

    float cs[4] = {0.f, 0.f, 0.f, 0.f};
    #pragma unroll
    for (int mi = 0; mi < 8; mi++) {
        #pragma unroll
        for (int reg = 0; reg < 4; reg++) {
            const int il = wr * 128 + mi * 16 + quad * 4 + reg;  // local row
            const int i  = r0 + il;
            const int ipos = i ^ B_HALF;
            float rs = 0.f;
            #pragma unroll
            for (int ni = 0; ni < 4; ni++) {
                const int j = c0 + wc * 64 + ni * 16 + nlo;
                const float sim = acc[mi][ni][reg] * INV_TAU;
                float e = __expf(sim - INV_TAU);
                if (diag && j == i) e = 0.f;          // exclude self
                if (posb && j == ipos) {              // unique writer per pair
                    pos_sims[i] = sim;
                    pos_sims[j] = sim;
                }
                rs += e;
                cs[ni] += e;
            }
            rs += __shfl_xor(rs, 1, 64);
            rs += __shfl_xor(rs, 2, 64);
            rs += __shfl_xor(rs, 4, 64);
            rs += __shfl_xor(rs, 8, 64);
            if (nlo == 0) rbuf[il * 4 + wc] = rs;
        }
    }
    if (!diag) {   // symmetric contribution to column rows (off-diag only)
        #pragma unroll
        for (int ni = 0; ni < 4; ni++) {
            float c = cs[ni];
            c += __shfl_xor(c, 16, 64);
            c += __shfl_xor(c, 32, 64);
            if (quad == 0) cbuf[(wc * 64 + ni * 16 + nlo) * 2 + wr] = c;
        }
    }
    __syncthreads();
    if (tid < 256) {
        const float s = rbuf[tid * 4] + rbuf[tid * 4 + 1]
                      + rbuf[tid * 4 + 2] + rbuf[tid * 4 + 3];
        atomicAdd(&row_sums[r0 + tid], s);
    } else if (!diag) {
        const int c = tid - 256;
        atomicAdd(&row_sums[c0 + c], cbuf[c * 2] + cbuf[c * 2 + 1]);
    }
#undef KTILE
#undef STAGE_A
#undef STAGE_B
}

// ---------------- kernel 3: loss per row + mean ----------------
__global__ __launch_bounds__(1024) void kfinal(const float* __restrict__ row_sums,
                                               const float* __restrict__ pos_sims,
                                               float* __restrict__ out) {
    const int tid = threadIdx.x;
    float acc = 0.f;
    for (int i = tid; i < N_TOT; i += 1024)
        acc += INV_TAU + __logf(row_sums[i]) - pos_sims[i];
    #pragma unroll
    for (int m = 1; m < 64; m <<= 1) acc += __shfl_xor(acc, m, 64);
    __shared__ float wsum[16];
    if ((tid & 63) == 0) wsum[tid >> 6] = acc;
    __syncthreads();
    if (tid < 16) {
        float v = wsum[tid];
        #pragma unroll
        for (int m = 1; m < 16; m <<= 1) v += __shfl_xor(v, m, 64);
        if (tid == 0) out[0] = v / (float)N_TOT;
    }
}

extern "C" void kernel_launch(void* const* d_in, const int* in_sizes, int n_in,
                              void* d_out, int out_size, void* d_ws, size_t ws_size,
                              hipStream_t stream) {
    const float* anchor   = (const float*)d_in[0];
    const float* positive = (const float*)d_in[1];
    float* out = (float*)d_out;

    char* ws = (char*)d_ws;
    __bf16* z        = (__bf16*)ws;                        // 8192*512*2 = 8 MB
    float*  row_sums = (float*)(ws + 8388608);             // 32 KB
    float*  pos_sims = (float*)(ws + 8388608 + 32768);     // 32 KB

    knorm<<<N_TOT / 4, 256, 0, stream>>>(anchor, positive, z, row_sums);
    ksim<<<528, 512, 0, stream>>>(z, row_sums, pos_sims);
    kfinal<<<1, 1024, 0, stream>>>(row_sums, pos_sims, out);
}

// Round 2
// 137.548 us; speedup vs baseline: 1.0080x; 1.0080x over previous
//
#include <hip/hip_runtime.h>
#include <hip/hip_bf16.h>
#include <stdint.h>

// NTXentLoss: B=4096, D=512, N=8192, tau=0.07, out = scalar mean loss.
// loss_i = -sim[i, i^B] + M + log( sum_{j != i} exp(sim_ij - M) ),  M = 1/tau
//
// R4: T2 LDS XOR-swizzle on the fragment reads. R3's frag read addr
// (row*64 + quad*16) put the 8 lanes sharing (row&1, quad) on one 4-bank
// group -> 4.0 conflict-cycles per ds_read_b128 (3.24M counted). Fix:
// chunk' = chunk ^ ((row>>1)&3), applied BOTH on the global_load_lds source
// (pre-swizzled per-lane global address, LDS dest stays linear as the HW
// requires) and on the ds_read address. Post-swizzle each bank group holds
// <=2 rows per 16-lane group = free (m136). kfinal split to 32 blocks +
// atomicAdd (out zeroed in knorm).

#define N_TOT   8192
#define B_HALF  4096
#define DDIM    512
#define INV_TAU 14.285714285714286f   // 1/0.07 == fixed logsumexp offset M
#define TTILES  32                    // 8192 / 256
#define NKT     16                    // 512 / 32

typedef __bf16 bf16x8 __attribute__((ext_vector_type(8)));
typedef __bf16 bf16x4 __attribute__((ext_vector_type(4)));
typedef float  floatx4 __attribute__((ext_vector_type(4)));

__device__ __forceinline__ void gl2lds16(const void* g, void* l) {
    __builtin_amdgcn_global_load_lds(
        (const __attribute__((address_space(1))) void*)g,
        (__attribute__((address_space(3))) void*)l, 16, 0, 0);
}

#define S_BARRIER() asm volatile("s_barrier" ::: "memory")
#define LGKM0()     do { asm volatile("s_waitcnt lgkmcnt(0)" ::: "memory"); \
                         __builtin_amdgcn_sched_barrier(0); } while (0)
#define VMCNT4()    asm volatile("s_waitcnt vmcnt(4)" ::: "memory")
#define VMCNT0()    asm volatile("s_waitcnt vmcnt(0)" ::: "memory")
#define VM_NONE()   do {} while (0)

// ---------------- kernel 1: normalize rows, fp32 -> bf16 z; zero row_sums ----
__global__ __launch_bounds__(256) void knorm(const float* __restrict__ anchor,
                                             const float* __restrict__ positive,
                                             __bf16* __restrict__ z,
                                             float* __restrict__ row_sums,
                                             float* __restrict__ out) {
    const int row  = blockIdx.x * 4 + (threadIdx.x >> 6);
    const int lane = threadIdx.x & 63;
    if (lane == 0) row_sums[row] = 0.0f;   // replaces hipMemsetAsync
    if (blockIdx.x == 0 && threadIdx.x == 0) out[0] = 0.0f;
    const float* src = (row < B_HALF) ? (anchor + (size_t)row * DDIM)
                                      : (positive + (size_t)(row - B_HALF) * DDIM);
    float4 v0 = ((const float4*)src)[lane];
    float4 v1 = ((const float4*)src)[lane + 64];
    float ss = v0.x*v0.x + v0.y*v0.y + v0.z*v0.z + v0.w*v0.w
             + v1.x*v1.x + v1.y*v1.y + v1.z*v1.z + v1.w*v1.w;
    #pragma unroll
    for (int m = 1; m < 64; m <<= 1) ss += __shfl_xor(ss, m, 64);
    const float inv = 1.0f / fmaxf(sqrtf(ss), 1e-8f);
    bf16x4 o0, o1;
    o0[0] = (__bf16)(v0.x*inv); o0[1] = (__bf16)(v0.y*inv);
    o0[2] = (__bf16)(v0.z*inv); o0[3] = (__bf16)(v0.w*inv);
    o1[0] = (__bf16)(v1.x*inv); o1[1] = (__bf16)(v1.y*inv);
    o1[2] = (__bf16)(v1.z*inv); o1[3] = (__bf16)(v1.w*inv);
    bf16x4* dst = (bf16x4*)(z + (size_t)row * DDIM);
    dst[lane]      = o0;
    dst[lane + 64] = o1;
}

// ---------------- kernel 2: upper-triangle 256x256 sim tiles, fused exp-sum --
// Grid 528 = 32*33/2 tile-pairs (rt <= ct). 512 threads = 8 waves (2M x 4N).
// Per wave: 128x64 of C as acc[8][4] 16x16x32 fragments. LDS: 4 K-slots of
// (A 256x32 + B 256x32) bf16 = 4 x 32 KiB. Counted vmcnt(4) pipeline,
// depth-2 prefetch; T2 chunk-XOR swizzle on staging source + frag reads.
__global__ __launch_bounds__(512, 2) void ksim(const __bf16* __restrict__ z,
                                               float* __restrict__ row_sums,
                                               float* __restrict__ pos_sims) {
    // XCD-chunked bijective swizzle (528 = 8 * 66), then triangular decode.
    int bid = (int)blockIdx.x;
    bid = (bid & 7) * 66 + (bid >> 3);
    int rem = bid, rt = 0;
    while (rem >= TTILES - rt) { rem -= TTILES - rt; rt++; }
    const int ct = rt + rem;
    const bool diag = (rt == ct);
    const bool posb = (ct == rt + 16);   // pos pair (i, i+4096) lives here

    const int r0 = rt * 256, c0 = ct * 256;
    const int tid  = threadIdx.x;
    const int w    = tid >> 6, lane = tid & 63;
    const int quad = lane >> 4, nlo = lane & 15;
    const int wr   = w >> 2,   wc  = w & 3;
    const int s4   = (nlo >> 1) & 3;     // read-side chunk swizzle (lane-const)

    __shared__ __align__(16) char smem[4][32768];   // slot = [A 16K][B 16K]

    // staging: wave-instruction covers 16 rows x 64 B; LDS dest is linear
    // (wave-uniform base + lane*16, the global_load_lds constraint); the
    // chunk permutation is applied on the GLOBAL source address instead:
    // lane L holds (row = base + L>>2, chunk = (L&3) ^ ((L>>3)&3)).
    const int schunk = ((lane & 3) ^ ((lane >> 3) & 3)) * 8;
    const __bf16* zA = z + (size_t)(r0 + w * 16 + (lane >> 2)) * DDIM + schunk;
    const __bf16* zB = z + (size_t)(c0 + w * 16 + (lane >> 2)) * DDIM + schunk;

#define STAGE_A(T2) do { char* s_ = smem[(T2) & 3]; const int kb_ = (T2) * 32;   \
        gl2lds16(zA + kb_,              s_ + w * 1024);                          \
        gl2lds16(zA + 128 * DDIM + kb_, s_ + 8192 + w * 1024); } while (0)
#define STAGE_B(T2) do { char* s_ = smem[(T2) & 3]; const int kb_ = (T2) * 32;   \
        gl2lds16(zB + kb_,              s_ + 16384 + w * 1024);                  \
        gl2lds16(zB + 128 * DDIM + kb_, s_ + 16384 + 8192 + w * 1024); } while (0)

    floatx4 acc[8][4];
    #pragma unroll
    for (int a = 0; a < 8; a++)
        #pragma unroll
        for (int b = 0; b < 4; b++) acc[a][b] = (floatx4){0.f, 0.f, 0.f, 0.f};

    // prologue: tiles 0 and 1 in flight (8 loads/thread), ensure tile 0 ready.
    STAGE_A(0); STAGE_B(0);
    STAGE_A(1); STAGE_B(1);
    VMCNT4();          // oldest 4 (tile 0) complete; tile 1's 4 stay in flight
    S_BARRIER();

    // Per K-tile: 2 phases x {ds_read frags | issue prefetch | barrier |
    // lgkm(0) | setprio(1) 16 MFMA setprio(0) | barrier}; vmcnt(4) once at
    // tile end guarantees tile t+1 resident before its first read.
#define KTILE(T, DO_STAGE, VMW) do {                                                  \
        char* As_ = smem[(T) & 3];                                                    \
        char* Bs_ = As_ + 16384;                                                      \
        bf16x8 af[4], bfr[4];                                                         \
        /* phase 0: rows wr*128 + 0..63 */                                            \
        _Pragma("unroll") for (int mi = 0; mi < 4; mi++)                              \
            af[mi] = *(const bf16x8*)(As_ + (wr * 128 + mi * 16 + nlo) * 64           \
                                          + ((quad ^ s4) * 16));                      \
        _Pragma("unroll") for (int ni = 0; ni < 4; ni++)                              \
            bfr[ni] = *(const bf16x8*)(Bs_ + (wc * 64 + ni * 16 + nlo) * 64           \
                                           + ((quad ^ s4) * 16));                     \
        if (DO_STAGE) STAGE_A((T) + 2);                                               \
        S_BARRIER(); LGKM0();                                                         \
        __builtin_amdgcn_s_setprio(1);                                                \
        _Pragma("unroll") for (int mi = 0; mi < 4; mi++)                              \
            _Pragma("unroll") for (int ni = 0; ni < 4; ni++)                          \
                acc[mi][ni] = __builtin_amdgcn_mfma_f32_16x16x32_bf16(                \
                    af[mi], bfr[ni], acc[mi][ni], 0, 0, 0);                           \
        __builtin_amdgcn_s_setprio(0);                                                \
        S_BARRIER();                                                                  \
        /* phase 1: rows wr*128 + 64..127 (bfr reused from regs) */                   \
        _Pragma("unroll") for (int mi = 0; mi < 4; mi++)                              \
            af[mi] = *(const bf16x8*)(As_ + (wr * 128 + 64 + mi * 16 + nlo) * 64      \
                                          + ((quad ^ s4) * 16));                      \
        if (DO_STAGE) STAGE_B((T) + 2);                                               \
        S_BARRIER(); LGKM0();                                                         \
        __builtin_amdgcn_s_setprio(1);                                                \
        _Pragma("unroll") for (int mi = 0; mi < 4; mi++)                              \
            _Pragma("unroll") for (int ni = 0; ni < 4; ni++)                          \
                acc[4 + mi][ni] = __builtin_amdgcn_mfma_f32_16x16x32_bf16(            \
                    af[mi], bfr[ni], acc[4 + mi][ni], 0, 0, 0);                       \
        __builtin_amdgcn_s_setprio(0);                                                \
        VMW();                                                                        \
        S_BARRIER();                                                                  \
    } while (0)

    for (int t = 0; t < NKT - 2; ++t) KTILE(t, true, VMCNT4);
    KTILE(NKT - 2, false, VMCNT0);
    KTILE(NKT - 1, false, VM_NONE);

    // ---------------- epilogue: exp, exclusions, LDS partial-reduce ----------
    __syncthreads();                       // all slot reads done; smem reusable
    float* rbuf = (float*)smem;            // [256][4] : row partial per wc-wave
    float* cbuf = (float*)(smem[0] + 4096);// [256][2] : col partial per wr-wave

    float cs[4] = {0.f, 0.f, 0.f, 0.f};
    #pragma unroll
    for (int mi = 0; mi < 8; mi++) {
        #pragma unroll
        for (int reg = 0; reg < 4; reg++) {
            const int il = wr * 128 + mi * 16 + quad * 4 + reg;  // local row
            const int i  = r0 + il;
            const int ipos = i ^ B_HALF;
            float rs = 0.f;
            #pragma unroll
            for (int ni = 0; ni < 4; ni++) {
                const int j = c0 + wc * 64 + ni * 16 + nlo;
                const float sim = acc[mi][ni][reg] * INV_TAU;
                float e = __expf(sim - INV_TAU);
                if (diag && j == i) e = 0.f;          // exclude self
                if (posb && j == ipos) {              // unique writer per pair
                    pos_sims[i] = sim;
                    pos_sims[j] = sim;
                }
                rs += e;
                cs[ni] += e;
            }
            rs += __shfl_xor(rs, 1, 64);
            rs += __shfl_xor(rs, 2, 64);
            rs += __shfl_xor(rs, 4, 64);
            rs += __shfl_xor(rs, 8, 64);
            if (nlo == 0) rbuf[il * 4 + wc] = rs;
        }
    }
    if (!diag) {   // symmetric contribution to column rows (off-diag only)
        #pragma unroll
        for (int ni = 0; ni < 4; ni++) {
            float c = cs[ni];
            c += __shfl_xor(c, 16, 64);
            c += __shfl_xor(c, 32, 64);
            if (quad == 0) cbuf[(wc * 64 + ni * 16 + nlo) * 2 + wr] = c;
        }
    }
    __syncthreads();
    if (tid < 256) {
        const float s = rbuf[tid * 4] + rbuf[tid * 4 + 1]
                      + rbuf[tid * 4 + 2] + rbuf[tid * 4 + 3];
        atomicAdd(&row_sums[r0 + tid], s);
    } else if (!diag) {
        const int c = tid - 256;
        atomicAdd(&row_sums[c0 + c], cbuf[c * 2] + cbuf[c * 2 + 1]);
    }
#undef KTILE
#undef STAGE_A
#undef STAGE_B
}

// ---------------- kernel 3: loss per row + mean (32 blocks, atomic out) -----
__global__ __launch_bounds__(256) void kfinal(const float* __restrict__ row_sums,
                                              const float* __restrict__ pos_sims,
                                              float* __restrict__ out) {
    const int r = blockIdx.x * 256 + threadIdx.x;
    float v = INV_TAU + __logf(row_sums[r]) - pos_sims[r];
    #pragma unroll
    for (int m = 1; m < 64; m <<= 1) v += __shfl_xor(v, m, 64);
    __shared__ float wsum[4];
    if ((threadIdx.x & 63) == 0) wsum[threadIdx.x >> 6] = v;
    __syncthreads();
    if (threadIdx.x == 0)
        atomicAdd(out, (wsum[0] + wsum[1] + wsum[2] + wsum[3]) * (1.0f / (float)N_TOT));
}

extern "C" void kernel_launch(void* const* d_in, const int* in_sizes, int n_in,
                              void* d_out, int out_size, void* d_ws, size_t ws_size,
                              hipStream_t stream) {
    const float* anchor   = (const float*)d_in[0];
    const float* positive = (const float*)d_in[1];
    float* out = (float*)d_out;

    char* ws = (char*)d_ws;
    __bf16* z        = (__bf16*)ws;                        // 8192*512*2 = 8 MB
    float*  row_sums = (float*)(ws + 8388608);             // 32 KB
    float*  pos_sims = (float*)(ws + 8388608 + 32768);     // 32 KB

    knorm<<<N_TOT / 4, 256, 0, stream>>>(anchor, positive, z, row_sums, out);
    ksim<<<528, 512, 0, stream>>>(z, row_sums, pos_sims);
    kfinal<<<N_TOT / 256, 256, 0, stream>>>(row_sums, pos_sims, out);
}